// Round 1
// baseline (1350.994 us; speedup 1.0000x reference)
//
#include <hip/hip_runtime.h>
#include <math.h>

// Glm4vMoeTextTopkRouter: logits = hs[32768,4096] @ wt[128,4096]^T in fp64 via
// v_mfma_f64_16x16x4_f64 (matrix pipe), then sigmoid/+bias/top-8 intra-wave.
// fp64 needed: index outputs compared exactly; fp32 accumulation flips ranks.
// R4: reg-staged prefetch double-buffer (T14). The next chunk's 12 global
// float4 loads are issued right after the compute barrier and consumed at the
// NEXT iteration's ds_write, so HBM latency (~900cy) hides under the ~8192cy
// MFMA phase instead of being drained inside the serial staging region.
// LDS read bases hoisted out of the K loop (ds_read with offset immediates).
#define TOKENS 32768
#define HDIM   4096
#define NEXP   128
#define TOPK   8
#define BT     64    // tokens per block (4 waves x 16)
#define BH     64    // K-chunk
#define LSTR   68    // LDS row stride (+4 pad: 272 B rows, 16B-aligned, bank scatter)

typedef __attribute__((ext_vector_type(4))) double dbl4;

__global__ __launch_bounds__(256, 2)
void glm4v_router_mfma(const float* __restrict__ hs,
                       const float* __restrict__ wt,
                       const float* __restrict__ bias,
                       float* __restrict__ out)
{
    __shared__ float As[BT * LSTR];     // [token][k], global layout copy
    __shared__ float Ws[NEXP * LSTR];   // [expert][k], global layout copy
    __shared__ float bias_s[NEXP];

    const int t    = threadIdx.x;
    const int w    = t >> 6;       // wave 0..3 -> tokens [w*16, w*16+16)
    const int lane = t & 63;
    const int col  = lane & 15;    // fed as: A token-row / B expert-col
    const int q    = lane >> 4;    // fed as: MFMA k-slot

    const int tokBase = blockIdx.x * BT;

    if (t < NEXP) bias_s[t] = bias[t];

    dbl4 acc[8];
    #pragma unroll
    for (int et = 0; et < 8; ++et) acc[et] = (dbl4){0.0, 0.0, 0.0, 0.0};

    // staging roles: sr = row 0..15, sc = float4 column offset (floats)
    const int sr = t >> 4;
    const int sc = (t & 15) * 4;

    // Hoisted LDS read bases (loop-invariant; inner loop uses offset imms).
    const float* __restrict__ aRow = As + (w * 16 + col) * LSTR + q * 4;
    const float* wBase[8];
    #pragma unroll
    for (int et = 0; et < 8; ++et)
        wBase[et] = Ws + (et * 16 + col) * LSTR + q * 4;

    // Hoisted global staging bases (advance by BH per chunk).
    const float* aSrc[4];
    const float* wSrc[8];
    #pragma unroll
    for (int j = 0; j < 4; ++j)
        aSrc[j] = hs + (size_t)(tokBase + sr + 16 * j) * HDIM + sc;
    #pragma unroll
    for (int j = 0; j < 8; ++j)
        wSrc[j] = wt + (size_t)(sr + 16 * j) * HDIM + sc;

    // Prefetch chunk 0 into registers.
    float4 a_pf[4];
    float4 w_pf[8];
    #pragma unroll
    for (int j = 0; j < 4; ++j) a_pf[j] = *(const float4*)(aSrc[j]);
    #pragma unroll
    for (int j = 0; j < 8; ++j) w_pf[j] = *(const float4*)(wSrc[j]);

    for (int hc = 0; hc < HDIM; hc += BH) {
        __syncthreads();   // previous chunk's readers done (also makes bias_s visible)

        // Commit prefetched regs -> LDS (compiler inserts the vmcnt wait here;
        // latency was covered by the previous chunk's MFMA phase).
        #pragma unroll
        for (int j = 0; j < 4; ++j)
            *(float4*)(As + (sr + 16 * j) * LSTR + sc) = a_pf[j];
        #pragma unroll
        for (int j = 0; j < 8; ++j)
            *(float4*)(Ws + (sr + 16 * j) * LSTR + sc) = w_pf[j];

        __syncthreads();

        // Issue next chunk's loads NOW; consumed at next iteration's ds_write.
        if (hc + BH < HDIM) {
            #pragma unroll
            for (int j = 0; j < 4; ++j)
                a_pf[j] = *(const float4*)(aSrc[j] + hc + BH);
            #pragma unroll
            for (int j = 0; j < 8; ++j)
                w_pf[j] = *(const float4*)(wSrc[j] + hc + BH);
        }

        // K-permutation trick: lane quarter q supplies logical k = kb + 4q + s
        // in MFMA #s; A and B agree on (q,s), so fragments are contiguous
        // float4 -> ds_read_b128, no transpose needed.
        #pragma unroll
        for (int kb = 0; kb < BH; kb += 16) {
            const float4 a4 = *(const float4*)(aRow + kb);
            float4 b4[8];
            #pragma unroll
            for (int et = 0; et < 8; ++et)
                b4[et] = *(const float4*)(wBase[et] + kb);
            const float* ap = (const float*)&a4;
            #pragma unroll
            for (int s = 0; s < 4; ++s) {
                const double ad = (double)ap[s];
                #pragma unroll
                for (int et = 0; et < 8; ++et) {
                    const double bd = (double)((const float*)&b4[et])[s];
                    acc[et] = __builtin_amdgcn_mfma_f64_16x16x4f64(ad, bd, acc[et], 0, 0, 0);
                }
            }
        }
    }

    // ---- D-layout calibration (2 constant MFMAs). With A[m][k] fed as m for
    // all k and B = 0.25: D[m][n] = m. With A = 0.25, B[k][n] = n: D[m][n] = n.
    // So rowcal[j]/colcal[j] tell this lane which (row, col) its acc slot j
    // holds, under whatever permutation the HW actually uses.
    dbl4 rowcal = (dbl4){0.0, 0.0, 0.0, 0.0};
    dbl4 colcal = (dbl4){0.0, 0.0, 0.0, 0.0};
    const double dcol = (double)col;
    rowcal = __builtin_amdgcn_mfma_f64_16x16x4f64(dcol, 0.25, rowcal, 0, 0, 0);
    colcal = __builtin_amdgcn_mfma_f64_16x16x4f64(0.25, dcol, colcal, 0, 0, 0);

    // ---- Epilogue (intra-wave). A token's 16 expert-holding lanes are the
    // 16-lane shuffle group sharing lane>>4 (rows depend only on (q, reg) in
    // every CDNA 16x16 D variant); labels come from the calibration.
    #pragma unroll
    for (int j = 0; j < 4; ++j) {
        const int rj = (int)(rowcal[j] + 0.5);   // token row in wave tile (0..15)
        const int cj = (int)(colcal[j] + 0.5);   // expert low index (0..15)
        const int tok = tokBase + w * 16 + rj;

        double ss[8];   // sigmoid (weight value)
        double rr[8];   // ranking value = sigmoid + bias
        #pragma unroll
        for (int et = 0; et < 8; ++et) {
            const double x = acc[et][j];
            const double s = 1.0 / (1.0 + exp(-x));
            ss[et] = s;
            rr[et] = s + (double)bias_s[et * 16 + cj];
        }

        int    sel[TOPK];
        double wv[TOPK];
        #pragma unroll
        for (int r = 0; r < TOPK; ++r) {
            // local max over 8 (strict > keeps lowest expert index; experts
            // et*16+cj ascend with et for fixed lane)
            double bv = rr[0]; int bi = cj; int bl = lane;
            #pragma unroll
            for (int et = 1; et < 8; ++et)
                if (rr[et] > bv) { bv = rr[et]; bi = et * 16 + cj; }
            // 16-lane butterfly carrying (value, expert, owner-lane);
            // stable tie-break: lower expert index wins
            #pragma unroll
            for (int m = 1; m <= 8; m <<= 1) {
                const double ov = __shfl_xor(bv, m, 64);
                const int    oi = __shfl_xor(bi, m, 64);
                const int    ol = __shfl_xor(bl, m, 64);
                if (ov > bv || (ov == bv && oi < bi)) { bv = ov; bi = oi; bl = ol; }
            }
            sel[r] = bi;
            // winner's exact sigmoid from its owner lane (static-index select)
            double sv = ss[0];
            #pragma unroll
            for (int et = 1; et < 8; ++et)
                if ((bi >> 4) == et) sv = ss[et];
            wv[r] = __shfl(sv, bl, 64);
            // mask winner on owner lane
            if (bl == lane) {
                #pragma unroll
                for (int et = 0; et < 8; ++et)
                    if ((bi >> 4) == et) rr[et] = -INFINITY;
            }
        }

        if (cj == 0) {   // exactly one lane per 16-lane group
            double denom = 1e-20;
            #pragma unroll
            for (int r = 0; r < TOPK; ++r) denom += wv[r];
            #pragma unroll
            for (int r = 0; r < TOPK; ++r) {
                out[(size_t)tok * TOPK + r] = (float)sel[r];   // indices half (as float)
                out[(size_t)TOKENS * TOPK + (size_t)tok * TOPK + r] = (float)(wv[r] / denom);
            }
        }
    }
}

extern "C" void kernel_launch(void* const* d_in, const int* in_sizes, int n_in,
                              void* d_out, int out_size, void* d_ws, size_t ws_size,
                              hipStream_t stream) {
    const float* hs   = (const float*)d_in[0];   // [32768, 4096] fp32
    const float* wt   = (const float*)d_in[1];   // [128, 4096] fp32
    const float* bias = (const float*)d_in[2];   // [128] fp32
    float* out = (float*)d_out;                  // [T*8] indices-as-float, then [T*8] weights

    dim3 grid(TOKENS / BT);   // 512 blocks, 2 per CU
    dim3 block(256);
    glm4v_router_mfma<<<grid, block, 0, stream>>>(hs, wt, bias, out);
}

// Round 5
// 1166.526 us; speedup vs baseline: 1.1581x; 1.1581x over previous
//
#include <hip/hip_runtime.h>
#include <math.h>

// Glm4vMoeTextTopkRouter: logits = hs[32768,4096] @ wt[128,4096]^T in fp64 via
// v_mfma_f64_16x16x4_f64 (matrix pipe), then sigmoid/+bias/top-8 intra-wave.
// fp64 needed: index outputs compared exactly; fp32 accumulation flips ranks.
//
// R5 (3rd resubmit; R2/R3/R4 benches were infra failures, kernel never ran):
// LDS eliminated entirely. Evidence from R4 rocprof: WRITE_SIZE=1.45GB (vs
// 2.1MB legit output) = scratch spill of the 48 prefetch VGPRs that had to
// live across s_barrier; MfmaUtil 54% = matrix pipe idle half the time.
// Dataflow analysis: each hs element is consumed by exactly ONE lane (no
// reuse -> LDS staging of A was pure overhead), and wt is 2MB = L2-resident.
// So: A fragments loaded global->reg double-buffered one chunk ahead (HBM
// ~900cy hidden under ~8192cy of MFMA); B fragments loaded L2->reg double-
// buffered one kb-group ahead (~400cy hidden under 2048cy MFMA burst); bias
// in 8 per-thread regs. Zero __shared__, zero __syncthreads, no barriers to
// force spills or lockstep drains. Numerics bit-identical to R4.
#define TOKENS 32768
#define HDIM   4096
#define NEXP   128
#define TOPK   8
#define BT     64    // tokens per block (4 waves x 16)
#define BH     64    // K-chunk (4 MFMA k-groups of 16)

typedef __attribute__((ext_vector_type(4))) double dbl4;

__global__ __launch_bounds__(256, 2)
void glm4v_router_mfma(const float* __restrict__ hs,
                       const float* __restrict__ wt,
                       const float* __restrict__ bias,
                       float* __restrict__ out)
{
    const int t    = threadIdx.x;
    const int w    = t >> 6;       // wave 0..3 -> tokens [w*16, w*16+16)
    const int lane = t & 63;
    const int col  = lane & 15;    // fed as: A token-row / B expert-col
    const int q    = lane >> 4;    // fed as: MFMA k-slot

    const int tokBase = blockIdx.x * BT;

    // per-thread bias for the 8 experts this lane's acc slots cover
    float bias_r[8];
    #pragma unroll
    for (int et = 0; et < 8; ++et) bias_r[et] = bias[et * 16 + col];

    dbl4 acc[8];
    #pragma unroll
    for (int et = 0; et < 8; ++et) acc[et] = (dbl4){0.0, 0.0, 0.0, 0.0};

    // Per-lane global fragment bases. K-permutation trick: lane quarter q
    // supplies logical k = kb + 4q + s in MFMA #s; A and B agree on (q,s),
    // so fragments are contiguous float4 global loads, no transpose.
    // Coalescing per instruction: 64 lanes = 16 rows x 64 contiguous bytes.
    const float* __restrict__ aPtr = hs + (size_t)(tokBase + w * 16 + col) * HDIM + q * 4;
    const float* wPtr[8];
    #pragma unroll
    for (int et = 0; et < 8; ++et)
        wPtr[et] = wt + (size_t)(et * 16 + col) * HDIM + q * 4;

    // prefetch chunk 0 A-fragments and kb=0 B-fragments
    float4 a_cur[4], a_nxt[4];
    float4 b_cur[8], b_nxt[8];
    #pragma unroll
    for (int kbi = 0; kbi < 4; ++kbi) a_cur[kbi] = *(const float4*)(aPtr + kbi * 16);
    #pragma unroll
    for (int kbi = 0; kbi < 4; ++kbi) a_nxt[kbi] = a_cur[kbi];
    #pragma unroll
    for (int et = 0; et < 8; ++et) b_cur[et] = *(const float4*)(wPtr[et]);
    #pragma unroll
    for (int et = 0; et < 8; ++et) b_nxt[et] = b_cur[et];

    for (int hc = 0; hc < HDIM; hc += BH) {
        // A prefetch for next chunk: HBM latency hides under this chunk's
        // ~8192cy of MFMA.
        if (hc + BH < HDIM) {
            #pragma unroll
            for (int kbi = 0; kbi < 4; ++kbi)
                a_nxt[kbi] = *(const float4*)(aPtr + hc + BH + kbi * 16);
        }
        #pragma unroll
        for (int kb4 = 0; kb4 < 4; ++kb4) {
            // B prefetch for next k-group (L2-hot): hides under 32 MFMAs.
            const int nko = hc + (kb4 + 1) * 16;
            if (nko < HDIM) {
                #pragma unroll
                for (int et = 0; et < 8; ++et)
                    b_nxt[et] = *(const float4*)(wPtr[et] + nko);
            }
            const float* ap = (const float*)&a_cur[kb4];
            #pragma unroll
            for (int s = 0; s < 4; ++s) {
                const double ad = (double)ap[s];
                #pragma unroll
                for (int et = 0; et < 8; ++et) {
                    const double bd = (double)((const float*)&b_cur[et])[s];
                    acc[et] = __builtin_amdgcn_mfma_f64_16x16x4f64(ad, bd, acc[et], 0, 0, 0);
                }
            }
            #pragma unroll
            for (int et = 0; et < 8; ++et) b_cur[et] = b_nxt[et];
        }
        #pragma unroll
        for (int kbi = 0; kbi < 4; ++kbi) a_cur[kbi] = a_nxt[kbi];
    }

    // ---- D-layout calibration (2 constant MFMAs). With A[m][k] fed as m for
    // all k and B = 0.25: D[m][n] = m. With A = 0.25, B[k][n] = n: D[m][n] = n.
    // So rowcal[j]/colcal[j] tell this lane which (row, col) its acc slot j
    // holds, under whatever permutation the HW actually uses.
    dbl4 rowcal = (dbl4){0.0, 0.0, 0.0, 0.0};
    dbl4 colcal = (dbl4){0.0, 0.0, 0.0, 0.0};
    const double dcol = (double)col;
    rowcal = __builtin_amdgcn_mfma_f64_16x16x4f64(dcol, 0.25, rowcal, 0, 0, 0);
    colcal = __builtin_amdgcn_mfma_f64_16x16x4f64(0.25, dcol, colcal, 0, 0, 0);

    // ---- Epilogue (intra-wave). A token's 16 expert-holding lanes are the
    // 16-lane shuffle group sharing lane>>4 (rows depend only on (q, reg) in
    // every CDNA 16x16 D variant); labels come from the calibration.
    #pragma unroll
    for (int j = 0; j < 4; ++j) {
        const int rj = (int)(rowcal[j] + 0.5);   // token row in wave tile (0..15)
        const int cj = (int)(colcal[j] + 0.5);   // expert low index (0..15)
        const int tok = tokBase + w * 16 + rj;

        double ss[8];   // sigmoid (weight value)
        double rr[8];   // ranking value = sigmoid + bias
        #pragma unroll
        for (int et = 0; et < 8; ++et) {
            const double x = acc[et][j];
            const double s = 1.0 / (1.0 + exp(-x));
            ss[et] = s;
            rr[et] = s + (double)bias_r[et];     // bias_r[et] == bias[et*16+cj]
        }

        int    sel[TOPK];
        double wv[TOPK];
        #pragma unroll
        for (int r = 0; r < TOPK; ++r) {
            // local max over 8 (strict > keeps lowest expert index; experts
            // et*16+cj ascend with et for fixed lane)
            double bv = rr[0]; int bi = cj; int bl = lane;
            #pragma unroll
            for (int et = 1; et < 8; ++et)
                if (rr[et] > bv) { bv = rr[et]; bi = et * 16 + cj; }
            // 16-lane butterfly carrying (value, expert, owner-lane);
            // stable tie-break: lower expert index wins
            #pragma unroll
            for (int m = 1; m <= 8; m <<= 1) {
                const double ov = __shfl_xor(bv, m, 64);
                const int    oi = __shfl_xor(bi, m, 64);
                const int    ol = __shfl_xor(bl, m, 64);
                if (ov > bv || (ov == bv && oi < bi)) { bv = ov; bi = oi; bl = ol; }
            }
            sel[r] = bi;
            // winner's exact sigmoid from its owner lane (static-index select)
            double sv = ss[0];
            #pragma unroll
            for (int et = 1; et < 8; ++et)
                if ((bi >> 4) == et) sv = ss[et];
            wv[r] = __shfl(sv, bl, 64);
            // mask winner on owner lane
            if (bl == lane) {
                #pragma unroll
                for (int et = 0; et < 8; ++et)
                    if ((bi >> 4) == et) rr[et] = -INFINITY;
            }
        }

        if (cj == 0) {   // exactly one lane per 16-lane group
            double denom = 1e-20;
            #pragma unroll
            for (int r = 0; r < TOPK; ++r) denom += wv[r];
            #pragma unroll
            for (int r = 0; r < TOPK; ++r) {
                out[(size_t)tok * TOPK + r] = (float)sel[r];   // indices half (as float)
                out[(size_t)TOKENS * TOPK + (size_t)tok * TOPK + r] = (float)(wv[r] / denom);
            }
        }
    }
}

extern "C" void kernel_launch(void* const* d_in, const int* in_sizes, int n_in,
                              void* d_out, int out_size, void* d_ws, size_t ws_size,
                              hipStream_t stream) {
    const float* hs   = (const float*)d_in[0];   // [32768, 4096] fp32
    const float* wt   = (const float*)d_in[1];   // [128, 4096] fp32
    const float* bias = (const float*)d_in[2];   // [128] fp32
    float* out = (float*)d_out;                  // [T*8] indices-as-float, then [T*8] weights

    dim3 grid(TOKENS / BT);   // 512 blocks, 2 per CU
    dim3 block(256);
    glm4v_router_mfma<<<grid, block, 0, stream>>>(hs, wt, bias, out);
}